// Round 3
// baseline (113.602 us; speedup 1.0000x reference)
//
#include <hip/hip_runtime.h>

#define TT 512
#define DD 256
#define BB 2
#define MM (BB*TT)          // 1024
#define LCH 16              // wkv chunk length

// ---------------------------------------------------------------------------
// K1: k/v/r = timemix(X) @ W^T, stored TRANSPOSED as (B, D, T) for the scan.
// Tile 32(t) x 32(n), 256 thr, micro 4t x 1n (acc=float4), K-chunks of 64.
// LDS tiles are k-contiguous [row][k] (pad 68 -> b128-aligned, <=2-way write
// conflicts).  Inner loop = dot-products; A-reads broadcast (2 distinct
// addrs/wave).  Global staging for chunk c+1 prefetched during chunk c FMAs.
// r is stored RAW (sigmoid applied in K2).
// ---------------------------------------------------------------------------
__global__ __launch_bounds__(256)
void gemm_mix_t(const float* __restrict__ X, const float* __restrict__ Xlast,
                const float* __restrict__ W0, const float* __restrict__ W1,
                const float* __restrict__ W2,
                const float* __restrict__ mx0, const float* __restrict__ mx1,
                const float* __restrict__ mx2,
                float* __restrict__ O0, float* __restrict__ O1,
                float* __restrict__ O2)
{
    const int mat = blockIdx.z;
    const float* W  = (mat == 0) ? W0  : (mat == 1) ? W1  : W2;
    const float* mx = (mat == 0) ? mx0 : (mat == 1) ? mx1 : mx2;
    float*       O  = (mat == 0) ? O0  : (mat == 1) ? O1  : O2;

    const int n0  = blockIdx.x * 32;
    const int m0  = blockIdx.y * 32;
    const int b   = m0 >> 9;            // / TT
    const int t0  = m0 & (TT - 1);
    const int tid = threadIdx.x;

    const int tm = tid >> 5;            // 0..7  (t-group of 4)
    const int tn = tid & 31;            // 0..31 (channel)

    __shared__ float As[32][68];        // [t][k]
    __shared__ float Bs[32][68];        // [n][k]

    // staging decomposition: idx = tid + p*256 -> row = idx>>4, c4 = (idx&15)*4
    const int rowS[2] = { tid >> 4, (tid + 256) >> 4 };
    const int c4S[2]  = { (tid & 15) * 4, (tid & 15) * 4 };

    float4 aR[2][2], wR[2][2];

    auto load_chunk = [&](int k0, float4 aO[2], float4 wO[2]) {
        #pragma unroll
        for (int p = 0; p < 2; ++p) {
            const int row = rowS[p], c4 = c4S[p];
            const float4 xc = *(const float4*)&X[(m0 + row) * DD + k0 + c4];
            float4 xp;
            if (t0 + row == 0) xp = *(const float4*)&Xlast[b * DD + k0 + c4];
            else               xp = *(const float4*)&X[(m0 + row - 1) * DD + k0 + c4];
            const float4 mv = *(const float4*)&mx[k0 + c4];
            aO[p].x = xp.x + (xc.x - xp.x) * mv.x;
            aO[p].y = xp.y + (xc.y - xp.y) * mv.y;
            aO[p].z = xp.z + (xc.z - xp.z) * mv.z;
            aO[p].w = xp.w + (xc.w - xp.w) * mv.w;
            wO[p] = *(const float4*)&W[(n0 + row) * DD + k0 + c4];
        }
    };

    float acc[4] = {0.f, 0.f, 0.f, 0.f};

    load_chunk(0, aR[0], wR[0]);

    for (int c = 0; c < 4; ++c) {
        const int cur = c & 1;
        #pragma unroll
        for (int p = 0; p < 2; ++p) {
            *(float4*)&As[rowS[p]][c4S[p]] = aR[cur][p];
            *(float4*)&Bs[rowS[p]][c4S[p]] = wR[cur][p];
        }
        __syncthreads();
        if (c < 3) load_chunk(64 * (c + 1), aR[cur ^ 1], wR[cur ^ 1]);
        #pragma unroll
        for (int k4 = 0; k4 < 16; ++k4) {
            const float4 bq = *(const float4*)&Bs[tn][k4 * 4];
            #pragma unroll
            for (int i = 0; i < 4; ++i) {
                const float4 aq = *(const float4*)&As[tm * 4 + i][k4 * 4];
                acc[i] = fmaf(aq.x, bq.x, acc[i]);
                acc[i] = fmaf(aq.y, bq.y, acc[i]);
                acc[i] = fmaf(aq.z, bq.z, acc[i]);
                acc[i] = fmaf(aq.w, bq.w, acc[i]);
            }
        }
        __syncthreads();
    }

    // acc = 4 consecutive t for channel n0+tn -> float4 store in (B,D,T)
    *(float4*)&O[(size_t)(b * DD + n0 + tn) * TT + t0 + tm * 4] =
        make_float4(acc[0], acc[1], acc[2], acc[3]);
}

// ---------------------------------------------------------------------------
// K2: WKV via chunked parallel scan.  64 blocks x 256 thr.
// Thread = (channel, chunk): ch = bid*8 + (tid>>5), chunk = tid&31 (L=16).
// Local Horner sums -> shfl_up scan over 32 chunks -> replay 16 steps.
// ---------------------------------------------------------------------------
__global__ __launch_bounds__(256)
void wkv_scan(const float* __restrict__ kT, const float* __restrict__ vT,
              const float* __restrict__ rT, const float* __restrict__ x,
              const float* __restrict__ last_num, const float* __restrict__ last_den,
              const float* __restrict__ time_decay, const float* __restrict__ time_first,
              float* __restrict__ yT, float* __restrict__ out)
{
    const int tid  = threadIdx.x;
    const int ch   = blockIdx.x * 8 + (tid >> 5);
    const int lane = tid & 31;           // chunk index
    const int b    = ch >> 8;
    const int d    = ch & (DD - 1);

    const float w  = -__expf(time_decay[d]);
    const float ew = __expf(w);
    const float eu = __expf(time_first[d]);

    const size_t base = (size_t)ch * TT + lane * LCH;
    float k_[LCH], v_[LCH], r_[LCH];
    #pragma unroll
    for (int i = 0; i < 4; ++i) {
        *(float4*)&k_[4 * i] = *(const float4*)(kT + base + 4 * i);
        *(float4*)&v_[4 * i] = *(const float4*)(vT + base + 4 * i);
        *(float4*)&r_[4 * i] = *(const float4*)(rT + base + 4 * i);
    }

    float ek[LCH], ekv[LCH], sr[LCH];
    #pragma unroll
    for (int i = 0; i < LCH; ++i) {
        ek[i]  = __expf(k_[i]);
        ekv[i] = ek[i] * v_[i];
        sr[i]  = __builtin_amdgcn_rcpf(1.0f + __expf(-r_[i]));
    }

    float A = __expf(w * (float)LCH);
    float Bn = 0.0f, Bd = 0.0f;
    #pragma unroll
    for (int i = 0; i < LCH; ++i) {
        Bn = fmaf(ew, Bn, ekv[i]);
        Bd = fmaf(ew, Bd, ek[i]);
    }

    #pragma unroll
    for (int s = 1; s < 32; s <<= 1) {
        const float Ax  = __shfl_up(A, s, 32);
        const float Bnx = __shfl_up(Bn, s, 32);
        const float Bdx = __shfl_up(Bd, s, 32);
        if (lane >= s) {
            Bn = fmaf(A, Bnx, Bn);
            Bd = fmaf(A, Bdx, Bd);
            A *= Ax;
        }
    }

    float Aex  = __shfl_up(A, 1, 32);
    float Bnex = __shfl_up(Bn, 1, 32);
    float Bdex = __shfl_up(Bd, 1, 32);
    if (lane == 0) { Aex = 1.0f; Bnex = 0.0f; Bdex = 0.0f; }
    float sn = fmaf(Aex, last_num[ch], Bnex);
    float sd = fmaf(Aex, last_den[ch], Bdex);

    float y_[LCH];
    #pragma unroll
    for (int i = 0; i < LCH; ++i) {
        const float euk = eu * ek[i];
        const float wkv = (sn + eu * ekv[i]) * __builtin_amdgcn_rcpf(sd + euk);
        y_[i] = wkv * sr[i];
        sn = fmaf(ew, sn, ekv[i]);
        sd = fmaf(ew, sd, ek[i]);
    }
    #pragma unroll
    for (int i = 0; i < 4; ++i)
        *(float4*)(yT + base + 4 * i) = *(const float4*)&y_[4 * i];

    if (lane == 31) {
        out[MM * DD + BB * DD + ch]     = sn;
        out[MM * DD + 2 * BB * DD + ch] = sd;
    }
    if (lane == 0)
        out[MM * DD + ch] = x[(b * TT + TT - 1) * DD + d];
}

// ---------------------------------------------------------------------------
// K3: out = yT^T @ Wo^T.  Tile 32(t) x 32(n), 256 thr (4 waves), micro 4t x 1n.
// A staged [k][t] (pad 36) straight from (B,D,T) -> b128 both ways.
// B staged [n][k] (pad 68).  Prefetch chunk c+1 during chunk c.
// ---------------------------------------------------------------------------
__global__ __launch_bounds__(256)
void gemm_out(const float* __restrict__ yT, const float* __restrict__ Wo,
              float* __restrict__ O)
{
    const int n0  = blockIdx.x * 32;
    const int m0  = blockIdx.y * 32;
    const int b   = m0 >> 9;
    const int t0  = m0 & (TT - 1);
    const int tid = threadIdx.x;

    const int tm = tid >> 5;            // 0..7
    const int tn = tid & 31;            // 0..31

    __shared__ float As[64][36];        // [k][t]
    __shared__ float Bs[32][68];        // [n][k]

    // A: 64 rows(k) x 8 float4(t); B: 32 rows(n) x 16 float4(k)
    const int rowA[2] = { tid >> 3, (tid + 256) >> 3 };
    const int c4A     = (tid & 7) * 4;
    const int rowB[2] = { tid >> 4, (tid + 256) >> 4 };
    const int c4B     = (tid & 15) * 4;

    float4 aR[2][2], wR[2][2];

    auto load_chunk = [&](int k0, float4 aO[2], float4 wO[2]) {
        #pragma unroll
        for (int p = 0; p < 2; ++p) {
            aO[p] = *(const float4*)&yT[(size_t)(b * DD + k0 + rowA[p]) * TT + t0 + c4A];
            wO[p] = *(const float4*)&Wo[(n0 + rowB[p]) * DD + k0 + c4B];
        }
    };

    float acc[4] = {0.f, 0.f, 0.f, 0.f};

    load_chunk(0, aR[0], wR[0]);

    for (int c = 0; c < 4; ++c) {
        const int cur = c & 1;
        #pragma unroll
        for (int p = 0; p < 2; ++p) {
            *(float4*)&As[rowA[p]][c4A] = aR[cur][p];
            *(float4*)&Bs[rowB[p]][c4B] = wR[cur][p];
        }
        __syncthreads();
        if (c < 3) load_chunk(64 * (c + 1), aR[cur ^ 1], wR[cur ^ 1]);
        #pragma unroll
        for (int k4 = 0; k4 < 16; ++k4) {
            const float4 bq = *(const float4*)&Bs[tn][k4 * 4];
            const float bb[4] = {bq.x, bq.y, bq.z, bq.w};
            #pragma unroll
            for (int j = 0; j < 4; ++j) {
                const float4 aq = *(const float4*)&As[k4 * 4 + j][tm * 4];
                acc[0] = fmaf(aq.x, bb[j], acc[0]);
                acc[1] = fmaf(aq.y, bb[j], acc[1]);
                acc[2] = fmaf(aq.z, bb[j], acc[2]);
                acc[3] = fmaf(aq.w, bb[j], acc[3]);
            }
        }
        __syncthreads();
    }

    #pragma unroll
    for (int i = 0; i < 4; ++i)
        O[(size_t)(m0 + tm * 4 + i) * DD + n0 + tn] = acc[i];
}

// ---------------------------------------------------------------------------
extern "C" void kernel_launch(void* const* d_in, const int* in_sizes, int n_in,
                              void* d_out, int out_size, void* d_ws, size_t ws_size,
                              hipStream_t stream)
{
    const float* x    = (const float*)d_in[0];
    const float* lx   = (const float*)d_in[1];
    const float* lnum = (const float*)d_in[2];
    const float* lden = (const float*)d_in[3];
    const float* td   = (const float*)d_in[4];
    const float* tf   = (const float*)d_in[5];
    const float* mk   = (const float*)d_in[6];
    const float* mv   = (const float*)d_in[7];
    const float* mr   = (const float*)d_in[8];
    const float* Wk   = (const float*)d_in[9];
    const float* Wv   = (const float*)d_in[10];
    const float* Wr   = (const float*)d_in[11];
    const float* Wo   = (const float*)d_in[12];
    float* out = (float*)d_out;

    float* kT = (float*)d_ws;          // (B, D, T)
    float* vT = kT + MM * DD;
    float* rT = vT + MM * DD;          // raw r (sigmoid applied in K2)
    float* yT = rT + MM * DD;          // (B, D, T) = wkv * sigmoid(r)

    gemm_mix_t<<<dim3(8, 32, 3), 256, 0, stream>>>(
        x, lx, Wk, Wv, Wr, mk, mv, mr, kT, vT, rT);

    wkv_scan<<<dim3(64), 256, 0, stream>>>(
        kT, vT, rT, x, lnum, lden, td, tf, yT, out);

    gemm_out<<<dim3(8, 32), 256, 0, stream>>>(yT, Wo, out);
}